// Round 1
// baseline (120.251 us; speedup 1.0000x reference)
//
#include <hip/hip_runtime.h>

#define B_    16
#define CIN_  128
#define COUT_ 128
#define N_    4096
#define K_    16

typedef __attribute__((ext_vector_type(8))) short bf16x8;  // 8 bf16 = 4 VGPR
typedef __attribute__((ext_vector_type(4))) float f32x4;
typedef __attribute__((ext_vector_type(4))) int   i32x4;

__device__ inline unsigned short f2bf(float f) {  // round-to-nearest-even
  unsigned u = __float_as_uint(f);
  u += 0x7fffu + ((u >> 16) & 1u);
  return (unsigned short)(u >> 16);
}

// Monotonic per-group barrier counters (8 groups = blocks sharing l&7, one
// XCD under round-robin dispatch; 128 B apart to avoid line contention).
// Zero-initialized once at module load; NEVER reset. Each launch consumes one
// epoch of exactly 32 increments per group, so graph replays / rocprof replays
// stay consistent: target = (base & ~31) + 32.
__device__ int g_bar[8 * 32];

// ---------------------------------------------------------------------------
// Fused kernel: 256 blocks x 1024 threads, 1 block/CU (LDS 108.5 KB caps
// blocks/CU at 1; grid == CU count => all blocks co-resident => spin barrier
// is deadlock-free).
// Phase 0: W fp32 -> bf16 LDS (per block; kills convW kernel + Wbf roundtrip)
// Phase 1: h[b][n][co] = bf16(relu(W x)), 256n x 128co tile via MFMA (as R9+)
// Barrier: per-group (l&7): RELEASE fetch_add (L2 writeback, lines stay
//          valid-clean) + RELAXED spin (no L2 invalidate) => phase-2 gathers
//          hit the producing XCD's L2. Correct under any placement: release
//          pushes h to L3; a consumer L2 can't hold stale h it didn't produce
//          (every kernel launch begins with a full L2 invalidate).
// Phase 2: out = mean_17(gather(h)) + bias; 4 concurrent 256-thread groups,
//          each exactly the proven R9 aggr block (64n x 128co).
// ---------------------------------------------------------------------------
__global__ __launch_bounds__(1024, 4) void fused_k(
    const float* __restrict__ W, const float* __restrict__ x,
    const int* __restrict__ ei, const float* __restrict__ bias,
    float* __restrict__ out, unsigned short* __restrict__ h) {
  __shared__ unsigned short Wl[128 * 136];                 // [co][ci]+8 pad, 34.8 KB
  __shared__ __align__(16) unsigned short He[256 * 144];   // [n][co]+16 pad, 73.7 KB
                                                           // (aliased by idx_t in ph2)
  const int tid  = threadIdx.x;
  const int l    = blockIdx.x;          // 0..255
  const int slot = l >> 3;              // 0..31
  const int b    = ((l & 7) << 1) | (slot >> 4);
  const int n0   = (slot & 15) * 256;

  const int lane = tid & 63;
  const int w    = tid >> 6;            // wave 0..15 -> n slice [n0+16w, +16)
  const int m    = lane & 15;
  const int quad = lane >> 4;

  // ---- issue the 32 strided x dword loads FIRST: their ~900cy HBM latency
  //      overlaps the W staging below (previously serialized behind a barrier)
  const float* xb = x + (size_t)b * CIN_ * N_ + n0 + 16 * w + m;
  float xa[32];
#pragma unroll
  for (int s = 0; s < 4; ++s)
#pragma unroll
    for (int j = 0; j < 8; ++j)
      xa[8 * s + j] = xb[(size_t)(32 * s + 8 * quad + j) * N_];

  // ---- phase 0: stage W fp32 -> bf16 -> LDS (each thread 2 x 8 floats,
  //      coalesced 32 B reads; identical RTE conversion to old convW_k)
#pragma unroll
  for (int r = 0; r < 2; ++r) {
    int id  = tid + 1024 * r;      // 0..2047 segments of 8 floats
    int co  = id >> 4;             // 0..127
    int seg = id & 15;
    const float4* wp = reinterpret_cast<const float4*>(W + co * CIN_ + 8 * seg);
    float4 v0 = wp[0];
    float4 v1 = wp[1];
    unsigned p0 = (unsigned)f2bf(v0.x) | ((unsigned)f2bf(v0.y) << 16);
    unsigned p1 = (unsigned)f2bf(v0.z) | ((unsigned)f2bf(v0.w) << 16);
    unsigned p2 = (unsigned)f2bf(v1.x) | ((unsigned)f2bf(v1.y) << 16);
    unsigned p3 = (unsigned)f2bf(v1.z) | ((unsigned)f2bf(v1.w) << 16);
    *reinterpret_cast<uint4*>(&Wl[co * 136 + 8 * seg]) =
        make_uint4(p0, p1, p2, p3);
  }
  __syncthreads();

  // ---- phase 1: MFMA gemm + ReLU, epilogue transpose through He ----
  bf16x8 a[4];
#pragma unroll
  for (int s = 0; s < 4; ++s)
#pragma unroll
    for (int j = 0; j < 8; ++j)
      a[s][j] = (short)f2bf(xa[8 * s + j]);

  const int nrow = 16 * w + 4 * quad;   // block-local n of c[0]
#pragma unroll
  for (int t = 0; t < 8; ++t) {   // 8 co-tiles of 16
    f32x4 c = {0.f, 0.f, 0.f, 0.f};
#pragma unroll
    for (int s = 0; s < 4; ++s) { // K = 4 x 32
      bf16x8 bf = *reinterpret_cast<const bf16x8*>(
          &Wl[(16 * t + m) * 136 + 32 * s + 8 * quad]);
      c = __builtin_amdgcn_mfma_f32_16x16x32_bf16(a[s], bf, c, 0, 0, 0);
    }
    int co = 16 * t + m;
#pragma unroll
    for (int r = 0; r < 4; ++r) {
      float v = c[r] > 0.f ? c[r] : 0.f;  // ReLU
      He[(nrow + r) * 144 + co] = f2bf(v);
    }
  }
  __syncthreads();

  {  // vectorized h store: 4 x dwordx4/thread, 1 KB contiguous per wave
    unsigned short* hb = h + ((size_t)b * N_ + n0) * COUT_;
    const int seg = tid & 15;
    const int nr  = tid >> 4;   // 0..63
#pragma unroll
    for (int p = 0; p < 4; ++p) {
      int n = nr + 64 * p;
      uint4 v = *reinterpret_cast<const uint4*>(&He[n * 144 + 8 * seg]);
      *reinterpret_cast<uint4*>(hb + (size_t)n * COUT_ + 8 * seg) = v;
    }
  }

  // ---- per-group barrier (32 blocks with the same l&7; they produce AND
  //      consume exactly h[2j], h[2j+1]) ----
  __syncthreads();   // implicit vmcnt(0) drain: this block's h stores in L2
  if (tid == 0) {
    int* cnt = &g_bar[(l & 7) * 32];
    // RELEASE @ agent scope: waitcnt + L2 writeback (lines stay valid-clean)
    int base = __hip_atomic_fetch_add(cnt, 1, __ATOMIC_RELEASE,
                                      __HIP_MEMORY_SCOPE_AGENT);
    int target = (base & ~31) + 32;   // end of this launch's epoch
    // RELAXED spin: atomic load reads the coherent point, no L2 invalidate
    while (__hip_atomic_load(cnt, __ATOMIC_RELAXED,
                             __HIP_MEMORY_SCOPE_AGENT) < target)
      __builtin_amdgcn_s_sleep(4);
  }
  __syncthreads();

  // ================= phase 2: gather + mean + bias =================
  // 4 concurrent 256-thread groups; group s4 == old aggr block l + 256*s4
  // (keeps l&7, hence batch-pair/XCD affinity).
  const int s4    = tid >> 8;                    // 0..3
  const int t2    = tid & 255;
  const int rest2 = (l >> 3) + 32 * s4;          // 0..127
  const int b2    = ((l & 7) << 1) | (rest2 >> 6);
  const int n02   = (rest2 & 63) * 64;
  int* idxs = reinterpret_cast<int*>(He) + s4 * (17 * 64);  // 17.4 KB total

  {  // stage+transpose neighbor indices (coalesced int4, NT to spare L2)
    int n  = t2 >> 2;        // 0..63
    int kq = t2 & 3;         // int4 along k
    i32x4 v = __builtin_nontemporal_load(
        reinterpret_cast<const i32x4*>(ei + ((size_t)b2 * N_ + n02 + n) * K_) + kq);
    idxs[(4 * kq + 0) * 64 + n] = v.x;
    idxs[(4 * kq + 1) * 64 + n] = v.y;
    idxs[(4 * kq + 2) * 64 + n] = v.z;
    idxs[(4 * kq + 3) * 64 + n] = v.w;
    if (t2 < 64) idxs[16 * 64 + t2] = n02 + t2;  // self loop
  }
  __syncthreads();

  const int q = t2 & 15;   // co = 8q..8q+7 (16 lanes = one 256 B h row)
  const int g = t2 >> 4;   // n_local = 4g .. 4g+3
  const unsigned short* hb2 = h + (size_t)b2 * N_ * COUT_;

  float acc[4][8];
#pragma unroll
  for (int j = 0; j < 4; ++j)
#pragma unroll
    for (int c = 0; c < 8; ++c) acc[j][c] = 0.f;

#pragma unroll 2
  for (int k = 0; k < 17; ++k) {
    uint4 v[4];
#pragma unroll
    for (int j = 0; j < 4; ++j) {
      int node = idxs[k * 64 + 4 * g + j];
      v[j] = *reinterpret_cast<const uint4*>(hb2 + (size_t)node * COUT_ + 8 * q);
    }
#pragma unroll
    for (int j = 0; j < 4; ++j) {
      acc[j][0] += __uint_as_float(v[j].x << 16);
      acc[j][1] += __uint_as_float(v[j].x & 0xffff0000u);
      acc[j][2] += __uint_as_float(v[j].y << 16);
      acc[j][3] += __uint_as_float(v[j].y & 0xffff0000u);
      acc[j][4] += __uint_as_float(v[j].z << 16);
      acc[j][5] += __uint_as_float(v[j].z & 0xffff0000u);
      acc[j][6] += __uint_as_float(v[j].w << 16);
      acc[j][7] += __uint_as_float(v[j].w & 0xffff0000u);
    }
  }

  const float norm = 1.0f / 17.0f;
  const float4 bv0 = *reinterpret_cast<const float4*>(bias + 8 * q);
  const float4 bv1 = *reinterpret_cast<const float4*>(bias + 8 * q + 4);
  float* ob = out + (size_t)b2 * COUT_ * N_ + n02 + 4 * g;
#pragma unroll
  for (int c = 0; c < 8; ++c) {
    int co = 8 * q + c;
    float bb = (c < 4) ? ((c == 0) ? bv0.x : (c == 1) ? bv0.y : (c == 2) ? bv0.z : bv0.w)
                       : ((c == 4) ? bv1.x : (c == 5) ? bv1.y : (c == 6) ? bv1.z : bv1.w);
    float4 r;
    r.x = acc[0][c] * norm + bb;
    r.y = acc[1][c] * norm + bb;
    r.z = acc[2][c] * norm + bb;
    r.w = acc[3][c] * norm + bb;
    *reinterpret_cast<float4*>(ob + (size_t)co * N_) = r;  // 16B, 64B/segment
  }
}

extern "C" void kernel_launch(void* const* d_in, const int* in_sizes, int n_in,
                              void* d_out, int out_size, void* d_ws, size_t ws_size,
                              hipStream_t stream) {
  const float* x    = (const float*)d_in[0];
  const int*   ei   = (const int*)d_in[1];   // [2][B][N][K]; plane 0
  const float* W    = (const float*)d_in[2];
  const float* bias = (const float*)d_in[3];
  float* out = (float*)d_out;
  unsigned short* h = (unsigned short*)d_ws;  // 16 MB

  fused_k<<<dim3(256), dim3(1024), 0, stream>>>(W, x, ei, bias, out, h);
}